// Round 2
// baseline (1436.200 us; speedup 1.0000x reference)
//
#include <hip/hip_runtime.h>

#define K_CODES 8192
#define DIM 256
#define NTOK 16384
#define NELEM 4194304  // 16*256*32*32

// ws layout (bytes):
// [0, 32768)       unsigned counts[8192]
// [32768, 98304)   int idx[16384]
// [98304, 98312)   double sumsq

__global__ __launch_bounds__(256) void k_init(unsigned* __restrict__ counts,
                                              double* __restrict__ sumsq) {
    int t = blockIdx.x * 256 + threadIdx.x;
    if (t < K_CODES) counts[t] = 0u;
    if (t == 0) *sumsq = 0.0;
}

// Fused scores + argmin, replicating the fp32 reference rounding:
//   d_k = fl(S - 2*M_k)   (||e_k||^2 is absorbed: < ulp(S)/2 always)
// with M_k accumulated as a single sequential fp32 FMA chain in ascending d,
// and argmin with lowest-index tie-break (matches np/jnp argmin on ties).
// Block = 256 threads, 64 tokens/block, grid = 256.
__global__ __launch_bounds__(256) void k_argmin(
    const float* __restrict__ x,      // [16,256,32,32] NCHW
    const float* __restrict__ w,      // [8192,256]
    int* __restrict__ idx_out,        // ws
    float* __restrict__ idxf_out,     // d_out indices region (as float)
    unsigned* __restrict__ counts) {
    __shared__ float lds_a[DIM][64];
    __shared__ float4 lds_b[512][8];
    __shared__ float sS[64];

    const int tid = threadIdx.x;
    const int n0 = blockIdx.x * 64;       // token base (64 | 1024 -> same batch)
    const int bb = n0 >> 10;
    const int hw0 = n0 & 1023;
    const float* xbase = x + (size_t)bb * DIM * 1024 + hw0;

    // ---- stage A: lds_a[d][m] ----
    {
        const int m4 = (tid & 15) * 4;
        #pragma unroll
        for (int it = 0; it < 16; ++it) {
            int d = it * 16 + (tid >> 4);
            float4 v = *reinterpret_cast<const float4*>(xbase + d * 1024 + m4);
            *reinterpret_cast<float4*>(&lds_a[d][m4]) = v;
        }
    }
    __syncthreads();

    // ---- per-token S = ||x||^2 (fp32; only the binade matters) ----
    if (tid < 64) {
        float s = 0.0f;
        for (int d = 0; d < DIM; ++d) {
            float v = lds_a[d][tid];
            s = fmaf(v, v, s);
        }
        sS[tid] = s;
    }
    __syncthreads();

    const int tx = tid & 31;   // 32 code groups (strided: k = tx + 32*c)
    const int ty = tid >> 5;   // 8 token groups (tokens ty*8 .. ty*8+7)

    float sv[8];
    #pragma unroll
    for (int r = 0; r < 8; ++r) sv[r] = sS[ty * 8 + r];

    float best[8];
    int bidx[8];
    #pragma unroll
    for (int r = 0; r < 8; ++r) { best[r] = 3.0e38f; bidx[r] = 0; }

    for (int k0 = 0; k0 < K_CODES; k0 += 512) {
        float acc[8][16];
        #pragma unroll
        for (int r = 0; r < 8; ++r)
            #pragma unroll
            for (int c = 0; c < 16; ++c) acc[r][c] = 0.0f;

        for (int dc = 0; dc < 8; ++dc) {
            __syncthreads();   // previous chunk's compute done
            {
                const int d4 = tid & 7;
                const int kb = tid >> 3;
                #pragma unroll
                for (int r = 0; r < 16; ++r) {
                    int kl = kb + (r << 5);
                    float4 v = *reinterpret_cast<const float4*>(
                        w + (size_t)(k0 + kl) * DIM + dc * 32 + d4 * 4);
                    lds_b[kl][d4 ^ (kl & 7)] = v;
                }
            }
            __syncthreads();

            #pragma unroll 1
            for (int s4 = 0; s4 < 8; ++s4) {
                const int d = dc * 32 + s4 * 4;
                #pragma unroll
                for (int ch = 0; ch < 2; ++ch) {
                    float4 breg[8];
                    #pragma unroll
                    for (int cc = 0; cc < 8; ++cc) {
                        int kl = tx + ((ch * 8 + cc) << 5);
                        breg[cc] = lds_b[kl][s4 ^ (kl & 7)];
                    }
                    #pragma unroll
                    for (int j = 0; j < 4; ++j) {
                        const float4* ar =
                            reinterpret_cast<const float4*>(&lds_a[d + j][0]);
                        float4 a0 = ar[2 * ty], a1 = ar[2 * ty + 1];
                        float av[8] = {a0.x, a0.y, a0.z, a0.w,
                                       a1.x, a1.y, a1.z, a1.w};
                        #pragma unroll
                        for (int cc = 0; cc < 8; ++cc) {
                            float bj = (&breg[cc].x)[j];
                            #pragma unroll
                            for (int t8 = 0; t8 < 8; ++t8)
                                acc[t8][ch * 8 + cc] =
                                    fmaf(av[t8], bj, acc[t8][ch * 8 + cc]);
                        }
                    }
                }
            }
        }

        // d_k = fl(S - 2*M_k): single fp32 rounding (x2 is exact), then
        // running argmin with lowest-index tie-break (kg ascends per lane).
        #pragma unroll
        for (int c = 0; c < 16; ++c) {
            int kg = k0 + tx + (c << 5);
            #pragma unroll
            for (int r = 0; r < 8; ++r) {
                float s = fmaf(-2.0f, acc[r][c], sv[r]);
                if (s < best[r]) {
                    best[r] = s;
                    bidx[r] = kg;
                }
            }
        }
    }

    // cross-lane argmin reduce over the 32 tx lanes (lowest-index tie-break)
    #pragma unroll
    for (int r = 0; r < 8; ++r) {
        float v = best[r];
        int i = bidx[r];
        for (int m = 16; m >= 1; m >>= 1) {
            float ov = __shfl_xor(v, m, 32);
            int oi = __shfl_xor(i, m, 32);
            if (ov < v || (ov == v && oi < i)) { v = ov; i = oi; }
        }
        if (tx == 0) {
            int n = n0 + ty * 8 + r;
            idx_out[n] = i;
            idxf_out[n] = (float)i;
            atomicAdd(&counts[i], 1u);
        }
    }
}

// gather + straight-through out + loss partial sum
__global__ __launch_bounds__(256) void k_out(
    const float* __restrict__ x, const float* __restrict__ w,
    const int* __restrict__ idx, float* __restrict__ out,
    double* __restrict__ sumsq) {
    const int t = threadIdx.x;
    const int n0 = (blockIdx.x & 255) * 64;
    const int d4 = (blockIdx.x >> 8) * 4 + (t >> 6);
    const int m = t & 63;
    const int n = n0 + m;
    const int bb = n >> 10, hw = n & 1023;
    const int k = idx[n];
    const float4 q4 = reinterpret_cast<const float4*>(w + (size_t)k * DIM)[d4];
    const float* xb = x + (size_t)bb * 262144 + hw;
    float* ob = out + (size_t)bb * 262144 + hw;
    const float qs[4] = {q4.x, q4.y, q4.z, q4.w};
    double local = 0.0;
    #pragma unroll
    for (int j = 0; j < 4; ++j) {
        int d = d4 * 4 + j;
        float xv = xb[(size_t)d * 1024];
        float diff = qs[j] - xv;           // (quantized - x) in fp32
        ob[(size_t)d * 1024] = xv + diff;  // x + (q - x), straight-through
        local += (double)diff * (double)diff;
    }
    for (int mm = 1; mm < 64; mm <<= 1) local += __shfl_xor(local, mm, 64);
    __shared__ double wsum[4];
    if ((t & 63) == 0) wsum[t >> 6] = local;
    __syncthreads();
    if (t == 0) atomicAdd(sumsq, wsum[0] + wsum[1] + wsum[2] + wsum[3]);
}

__global__ __launch_bounds__(256) void k_fin(const unsigned* __restrict__ counts,
                                             const double* __restrict__ sumsq,
                                             float* __restrict__ loss_out,
                                             float* __restrict__ perp_out) {
    __shared__ double sh[256];
    double h = 0.0;
    for (int k = threadIdx.x; k < K_CODES; k += 256) {
        double p = (double)counts[k] * (1.0 / 16384.0);
        h -= p * log(p + 1e-10);
    }
    sh[threadIdx.x] = h;
    __syncthreads();
    for (int s = 128; s > 0; s >>= 1) {
        if (threadIdx.x < s) sh[threadIdx.x] += sh[threadIdx.x + s];
        __syncthreads();
    }
    if (threadIdx.x == 0) {
        *perp_out = (float)exp(sh[0]);
        *loss_out = (float)(1.25 * (*sumsq) * (1.0 / 4194304.0));
    }
}

extern "C" void kernel_launch(void* const* d_in, const int* in_sizes, int n_in,
                              void* d_out, int out_size, void* d_ws, size_t ws_size,
                              hipStream_t stream) {
    const float* x = (const float*)d_in[0];
    const float* w = (const float*)d_in[1];
    float* out = (float*)d_out;
    char* ws = (char*)d_ws;

    unsigned* counts = (unsigned*)ws;
    int* idx = (int*)(ws + 32768);
    double* sumsq = (double*)(ws + 98304);

    float* loss_out = out;                 // [0]
    float* out_t = out + 1;                // [1 .. 4194304]
    float* perp_out = out + 1 + NELEM;     // [4194305]
    float* idxf = out + 2 + NELEM;         // [4194306 ..]

    k_init<<<32, 256, 0, stream>>>(counts, sumsq);
    k_argmin<<<256, 256, 0, stream>>>(x, w, idx, idxf, counts);
    k_out<<<4096, 256, 0, stream>>>(x, w, idx, out_t, sumsq);
    k_fin<<<1, 256, 0, stream>>>(counts, sumsq, loss_out, perp_out);
}